// Round 1
// baseline (424.137 us; speedup 1.0000x reference)
//
#include <hip/hip_runtime.h>

// Cost-volume builder:
// out[b, c2, d, h, w] with shape (4, 64, 48, 64, 128) fp32
//   c2 <  32: (w >= d) ? left [b, c2,    h, w    ] : 0
//   c2 >= 32: (w >= d) ? right[b, c2-32, h, w - d] : 0
//
// Write-bound: 402.7 MB out, 8 MB in (inputs live in L2/L3 across the D reuse).

#define BB 4
#define CC 32
#define HH 64
#define WW 128
#define DD 48

__global__ __launch_bounds__(256) void cost_kernel(
    const float* __restrict__ left,
    const float* __restrict__ right,
    float* __restrict__ out)
{
    // grid: (H*W/4/256 = 8, D = 48, B*2C = 256)
    const int p  = blockIdx.x * 256 + threadIdx.x;  // float4 index within (h,w) plane
    const int d  = blockIdx.y;
    const int bc = blockIdx.z;                      // b*64 + c2
    const int b  = bc >> 6;
    const int c2 = bc & 63;
    const int h  = p >> 5;                          // W/4 = 32 float4 per row
    const int w0 = (p & 31) * 4;                    // starting w of this float4

    const bool is_right = (c2 >= CC);               // uniform per block
    const int  c        = is_right ? (c2 - CC) : c2;
    const float* __restrict__ src = is_right ? right : left;
    const float* __restrict__ row = src + ((((size_t)b * CC + c) * HH + h) * WW);

    float v[4];
    if (!is_right) {
        // aligned vector load, then mask w < d to zero
        const float4 lv = *reinterpret_cast<const float4*>(row + w0);
        v[0] = lv.x; v[1] = lv.y; v[2] = lv.z; v[3] = lv.w;
        if (w0 < d) {
            #pragma unroll
            for (int i = 0; i < 4; ++i)
                if (w0 + i < d) v[i] = 0.0f;
        }
    } else {
        if (d <= w0) {
            // all 4 in range: consecutive (unaligned by d) reads, L1/L2-resident
            #pragma unroll
            for (int i = 0; i < 4; ++i) v[i] = row[w0 + i - d];
        } else if (d > w0 + 3) {
            #pragma unroll
            for (int i = 0; i < 4; ++i) v[i] = 0.0f;
        } else {
            #pragma unroll
            for (int i = 0; i < 4; ++i) {
                const int ws = w0 + i - d;
                v[i] = (ws >= 0) ? row[ws] : 0.0f;
            }
        }
    }

    float4 o;
    o.x = v[0]; o.y = v[1]; o.z = v[2]; o.w = v[3];
    float4* __restrict__ out4 = reinterpret_cast<float4*>(out);
    out4[((size_t)bc * DD + d) * (HH * WW / 4) + p] = o;
}

extern "C" void kernel_launch(void* const* d_in, const int* in_sizes, int n_in,
                              void* d_out, int out_size, void* d_ws, size_t ws_size,
                              hipStream_t stream)
{
    const float* left  = (const float*)d_in[0];
    const float* right = (const float*)d_in[1];
    float* out = (float*)d_out;

    dim3 grid(HH * WW / 4 / 256, DD, BB * 2 * CC);  // (8, 48, 256)
    cost_kernel<<<grid, dim3(256), 0, stream>>>(left, right, out);
}

// Round 3
// 422.833 us; speedup vs baseline: 1.0031x; 1.0031x over previous
//
#include <hip/hip_runtime.h>

// Cost-volume builder:
// out[b, c2, d, h, w] with shape (4, 64, 48, 64, 128) fp32
//   c2 <  32: (w >= d) ? left [b, c2,    h, w    ] : 0
//   c2 >= 32: (w >= d) ? right[b, c2-32, h, w - d] : 0
//
// Write-bound: 402.7 MB out vs 8 MB in (inputs L2/L3-resident across D=48 reuse).
// R3: nontemporal float4 stores via clang ext-vector type (HIP float4 is a
// class type the builtin rejects). Output stream (403 MB) exceeds L3 (256 MiB);
// caching it only thrashes — stream straight to HBM with `nt` stores.

#define BB 4
#define CC 32
#define HH 64
#define WW 128
#define DD 48

typedef float vfloat4 __attribute__((ext_vector_type(4)));

__global__ __launch_bounds__(256) void cost_kernel(
    const float* __restrict__ left,
    const float* __restrict__ right,
    float* __restrict__ out)
{
    // grid: (H*W/4/256 = 8, D = 48, B*2C = 256)
    const int p  = blockIdx.x * 256 + threadIdx.x;  // float4 index within (h,w) plane
    const int d  = blockIdx.y;
    const int bc = blockIdx.z;                      // b*64 + c2
    const int b  = bc >> 6;
    const int c2 = bc & 63;
    const int h  = p >> 5;                          // W/4 = 32 float4 per row
    const int w0 = (p & 31) * 4;                    // starting w of this float4

    const bool is_right = (c2 >= CC);               // uniform per block
    const int  c        = is_right ? (c2 - CC) : c2;
    const float* __restrict__ src = is_right ? right : left;
    const float* __restrict__ row = src + ((((size_t)b * CC + c) * HH + h) * WW);

    float v[4];
    if (!is_right) {
        // aligned vector load, then mask w < d to zero
        const vfloat4 lv = *reinterpret_cast<const vfloat4*>(row + w0);
        v[0] = lv.x; v[1] = lv.y; v[2] = lv.z; v[3] = lv.w;
        if (w0 < d) {
            #pragma unroll
            for (int i = 0; i < 4; ++i)
                if (w0 + i < d) v[i] = 0.0f;
        }
    } else {
        if (d <= w0) {
            // all 4 in range: consecutive (unaligned by d) reads, L1/L2-resident
            #pragma unroll
            for (int i = 0; i < 4; ++i) v[i] = row[w0 + i - d];
        } else if (d > w0 + 3) {
            #pragma unroll
            for (int i = 0; i < 4; ++i) v[i] = 0.0f;
        } else {
            #pragma unroll
            for (int i = 0; i < 4; ++i) {
                const int ws = w0 + i - d;
                v[i] = (ws >= 0) ? row[ws] : 0.0f;
            }
        }
    }

    vfloat4 o;
    o.x = v[0]; o.y = v[1]; o.z = v[2]; o.w = v[3];
    vfloat4* __restrict__ out4 = reinterpret_cast<vfloat4*>(out);
    __builtin_nontemporal_store(o, &out4[((size_t)bc * DD + d) * (HH * WW / 4) + p]);
}

extern "C" void kernel_launch(void* const* d_in, const int* in_sizes, int n_in,
                              void* d_out, int out_size, void* d_ws, size_t ws_size,
                              hipStream_t stream)
{
    const float* left  = (const float*)d_in[0];
    const float* right = (const float*)d_in[1];
    float* out = (float*)d_out;

    dim3 grid(HH * WW / 4 / 256, DD, BB * 2 * CC);  // (8, 48, 256)
    cost_kernel<<<grid, dim3(256), 0, stream>>>(left, right, out);
}